// Round 7
// baseline (1243.656 us; speedup 1.0000x reference)
//
#include <hip/hip_runtime.h>

#define NN 8192      // nodes
#define SS 20        // seq len
#define DD 256       // feat dim = H
#define RGATE 1024   // 4H
#define KKD 512      // D + H

typedef __attribute__((ext_vector_type(8))) short short8;
typedef __attribute__((ext_vector_type(4))) float f32x4;

__device__ __forceinline__ unsigned short f2bf(float f) {
    unsigned int u = __float_as_uint(f);
    u += 0x7FFFu + ((u >> 16) & 1u);   // round-to-nearest-even
    return (unsigned short)(u >> 16);
}

__device__ __forceinline__ void async_copy16(const void* g, void* l) {
    __builtin_amdgcn_global_load_lds(
        (const __attribute__((address_space(1))) void*)g,
        (__attribute__((address_space(3))) void*)l, 16, 0, 0);
}

__device__ __forceinline__ float sigm(float x) { return 1.0f / (1.0f + __expf(-x)); }
__device__ __forceinline__ float tanh_(float x) { return 2.0f / (1.0f + __expf(-2.0f * x)) - 1.0f; }

// ---------------------------------------------------------------------------
// Weight repack: Wcat[dir][r'][k], r' = 4*j + gate; k<256 -> w_ih, else w_hh.
// ---------------------------------------------------------------------------
__global__ void convert_w(const float* __restrict__ wihf, const float* __restrict__ whhf,
                          const float* __restrict__ bf,   const float* __restrict__ wihb,
                          const float* __restrict__ whhb, const float* __restrict__ bb,
                          unsigned short* __restrict__ Wcat, float* __restrict__ bperm) {
    const int idx = blockIdx.x * 256 + threadIdx.x;   // < 2*1024*512
    const int dir = idx >> 19;
    const int rem = idx & ((1 << 19) - 1);
    const int rp  = rem >> 9;          // r' in [0,1024)
    const int k   = rem & 511;
    const int j   = rp >> 2, gi = rp & 3;
    const int r   = gi * 256 + j;      // original row (PyTorch i,f,g,o blocks)
    const float* wih = dir ? wihb : wihf;
    const float* whh = dir ? whhb : whhf;
    const float v = (k < 256) ? wih[r * 256 + k] : whh[r * 256 + (k - 256)];
    Wcat[idx] = f2bf(v);
    if (k == 0) {
        const float* b = dir ? bb : bf;
        bperm[dir * 1024 + rp] = b[r];
    }
}

// ---------------------------------------------------------------------------
// Persistent fused kernel: gather + 20 bidirectional LSTM steps + reduce +
// broadcast-out. Grid 256 x 512 thr. LDS 128 KB forces 1 block/CU => all 256
// blocks co-resident (grid <= #CU) => custom barriers are deadlock-free
// WITHOUT cooperative launch.
// Block decode: dir=b&1, nblk=(b>>3)&3 (64 hidden units = 256 gate cols),
// mslab=(((b&7)>>1)<<3)|(b>>5) (256 node rows). The ONLY cross-block dep is
// h between the 4 blocks sharing (dir,mslab) -> 4-block monotonic barrier
// bar[dir*32+mslab] per step; final 8-block barrier bar2[mslab] before out.
// Per step: 8 rounds BK=64, A(256x64)/B(256x64) LDS double-buffer staged by
// global_load_lds w/ XOR-8 seg swizzle (conflict-free, R3/R6-verified).
// Rounds 0-3 = x-half (no h dep) run BEFORE the h-spin -> barrier hidden.
// c state in REGISTERS (cst[2][4], block owns rows x its 64 units).
// v-side budget (split rule, R2/R4/R5/R6 evidence): 128; est ~120 use.
// acc[4][8] = 128 AGPRs exactly.
// ---------------------------------------------------------------------------
__global__ __launch_bounds__(512, 2) void lstm_persist(
    const float* __restrict__ emb,             // [V][256] f32
    const int* __restrict__ nidx,              // [NN][SS] int32
    unsigned short* X,                         // [SS][NN][256] bf16 (ws)
    const unsigned short* __restrict__ Wcat,   // [2][1024][512] bf16
    const float* __restrict__ bperm,           // [2][1024]
    unsigned short* hping,                     // [2 ping][2 dir][NN][256] bf16
    float* hsum,                               // [NN] f32
    int* bar, int* bar2,                       // [64], [32] monotonic counters
    float* out) {                              // [NN][512] f32
    const int b     = blockIdx.x;
    const int dir   = b & 1;
    const int nblk  = (b >> 3) & 3;
    const int mslab = (((b & 7) >> 1) << 3) | (b >> 5);
    const int grp   = dir * 32 + mslab;
    const int m0    = mslab * 256;
    const int n0    = nblk * 256;

    const unsigned short* W  = Wcat + (size_t)dir * RGATE * KKD;
    const float*          bp = bperm + dir * RGATE;

    __shared__ __align__(16) char smem[131072];   // A0 A1 B0 B1, 32 KB each

    const int tid  = threadIdx.x;
    const int lane = tid & 63;
    const int w    = tid >> 6;        // 0..7
    const int wm   = w >> 1, wn = w & 1;
    const int quad = lane >> 4, l15 = lane & 15;
    const int jq   = lane & 3,  rl  = lane >> 2;
    const int lrow8 = lane >> 3, lseg8 = lane & 7, sxor = l15 & 7;

    // ---- gather prologue: this block's 64 rows x 20 t of X ----
    {
        const int g0 = m0 + nblk * 64;
        for (int p = w; p < 160; p += 8) {        // 20 iters/wave
            const int t  = p >> 3;
            const int i0 = (p & 7) * 8;
            #pragma unroll
            for (int i = 0; i < 8; ++i) {
                const int n  = g0 + i0 + i;
                const int er = nidx[n * SS + t];
                const float4 v = ((const float4*)(emb + (size_t)er * DD))[lane];
                ushort4 o;
                o.x = f2bf(v.x); o.y = f2bf(v.y); o.z = f2bf(v.z); o.w = f2bf(v.w);
                ((ushort4*)(X + ((size_t)t * NN + n) * DD))[lane] = o;
            }
        }
    }
    __syncthreads();                               // per-wave vmcnt drained
    if (tid == 0) {
        __threadfence();
        atomicAdd(&bar[grp], 1);
        while (__hip_atomic_load(&bar[grp], __ATOMIC_ACQUIRE,
                                 __HIP_MEMORY_SCOPE_AGENT) < 4)
            __builtin_amdgcn_s_sleep(2);
    }
    __syncthreads();

    // ---- persistent LSTM state ----
    f32x4 cst[2][4];                  // c in registers [half][mt]
    #pragma unroll
    for (int i = 0; i < 2; ++i)
        #pragma unroll
        for (int j = 0; j < 4; ++j) cst[i][j] = f32x4{0.f, 0.f, 0.f, 0.f};
    float hs[4] = {0.f, 0.f, 0.f, 0.f};
    f32x4 acc[4][8];

    const unsigned short* Xt = nullptr;
    const unsigned short* hprev = nullptr;
    unsigned short* hnext = nullptr;

    auto stage = [&](int r, int buf) {            // round r (0..7), BK=64
        const int k0s = (r & 3) * 64;
        const unsigned short* Asrc = (r < 4) ? Xt : hprev;
        char* Ad = smem + buf * 32768;
        char* Bd = smem + 65536 + buf * 32768;
        #pragma unroll
        for (int i = 0; i < 4; ++i) {
            const int row  = w * 32 + i * 8 + lrow8;      // 0..255
            const int gofs = (lseg8 ^ (row & 7)) * 8;     // shorts
            async_copy16(Asrc + (size_t)(m0 + row) * DD + k0s + gofs,
                         (void*)(Ad + (w * 32 + i * 8) * 128));
            async_copy16(W + (size_t)(n0 + row) * KKD + r * 64 + gofs,
                         (void*)(Bd + (w * 32 + i * 8) * 128));
        }
    };

    auto compute = [&](int buf) {
        const char* Ab = smem + buf * 32768;
        const char* Bb = smem + 65536 + buf * 32768;
        #pragma unroll
        for (int kk = 0; kk < 2; ++kk) {
            short8 af[4], bfr[8];
            const int so = ((kk * 4 + quad) ^ sxor) << 4;
            #pragma unroll
            for (int mt = 0; mt < 4; ++mt)
                af[mt] = *(const short8*)(Ab + (wm * 64 + mt * 16 + l15) * 128 + so);
            #pragma unroll
            for (int nt = 0; nt < 8; ++nt)
                bfr[nt] = *(const short8*)(Bb + (wn * 128 + nt * 16 + l15) * 128 + so);
            #pragma unroll
            for (int mt = 0; mt < 4; ++mt)
                #pragma unroll
                for (int nt = 0; nt < 8; ++nt)
                    acc[mt][nt] = __builtin_amdgcn_mfma_f32_16x16x32_bf16(
                        af[mt], bfr[nt], acc[mt][nt], 0, 0, 0);
        }
    };

    for (int s = 0; s < SS; ++s) {
        const int t = dir ? (SS - 1 - s) : s;
        Xt    = X + (size_t)t * NN * DD;
        hprev = hping + ((size_t)((s & 1) * 2 + dir)) * NN * 256;
        hnext = hping + ((size_t)((((s + 1) & 1) * 2) + dir)) * NN * 256;

        #pragma unroll
        for (int i = 0; i < 4; ++i)
            #pragma unroll
            for (int j = 0; j < 8; ++j) acc[i][j] = f32x4{0.f, 0.f, 0.f, 0.f};

        // x-half rounds (no h dependency) — run while siblings finish h
        stage(0, 0);
        __syncthreads();
        for (int r = 0; r < 4; ++r) {
            if (r < 3) stage(r + 1, (r + 1) & 1);
            compute(r & 1);
            __syncthreads();
        }
        // h-visibility gate (4-block group, monotonic target)
        if (s > 0) {
            if (tid == 0)
                while (__hip_atomic_load(&bar[grp], __ATOMIC_ACQUIRE,
                                         __HIP_MEMORY_SCOPE_AGENT) < 4 * s + 4)
                    __builtin_amdgcn_s_sleep(2);
            __syncthreads();
        }
        // h-half rounds
        stage(4, 0);
        __syncthreads();
        for (int r = 4; r < 8; ++r) {
            if (r < 7) stage(r + 1, (r + 1) & 1);
            compute(r & 1);
            __syncthreads();
        }

        // ---- epilogue: regroup gates via wave-private LDS, cell update ----
        float* my = (float*)smem + w * 1088;      // 16 x 68 floats
        #pragma unroll
        for (int half = 0; half < 2; ++half) {
            const int j0 = nblk * 64 + wn * 32 + half * 16 + jq * 4;
            f32x4 bias4[4];
            #pragma unroll
            for (int jj = 0; jj < 4; ++jj)
                bias4[jj] = *(const f32x4*)(bp + 4 * (j0 + jj));
            #pragma unroll
            for (int mt = 0; mt < 4; ++mt) {
                #pragma unroll
                for (int nt = 0; nt < 4; ++nt) {
                    const int ntg = half * 4 + nt;
                    #pragma unroll
                    for (int v = 0; v < 4; ++v)
                        my[(quad * 4 + v) * 68 + nt * 16 + l15] = acc[mt][ntg][v];
                }
                asm volatile("s_waitcnt lgkmcnt(0)" ::: "memory");
                const int mg = m0 + wm * 64 + mt * 16 + rl;
                f32x4 cold = cst[half][mt], cnew;
                ushort4 hp;
                float lsum = 0.f;
                #pragma unroll
                for (int jj = 0; jj < 4; ++jj) {
                    f32x4 g  = *(const f32x4*)(my + rl * 68 + (jq * 4 + jj) * 4);
                    f32x4 bb = bias4[jj];
                    const float gi = sigm(g.x + bb.x);   // i
                    const float gf = sigm(g.y + bb.y);   // f
                    const float gg = tanh_(g.z + bb.z);  // g
                    const float go = sigm(g.w + bb.w);   // o
                    const float cn = gf * cold[jj] + gi * gg;
                    cnew[jj] = cn;
                    const float hv = go * tanh_(cn);
                    lsum += hv;
                    ((unsigned short*)&hp)[jj] = f2bf(hv);
                }
                cst[half][mt] = cnew;
                *(ushort4*)(hnext + (size_t)mg * 256 + j0) = hp;
                hs[mt] += lsum;
            }
        }
        __syncthreads();          // epilogue scratch free before next stage(0)
        if (tid == 0 && s < SS - 1) {
            __threadfence();
            atomicAdd(&bar[grp], 1);
        }
    }

    // ---- final reduction: hs -> hsum atomics ----
    #pragma unroll
    for (int mt = 0; mt < 4; ++mt) {
        float v = hs[mt];
        v += __shfl_xor(v, 1);
        v += __shfl_xor(v, 2);
        if (jq == 0) atomicAdd(&hsum[m0 + wm * 64 + mt * 16 + rl], v);
    }
    __syncthreads();
    if (tid == 0) {
        __threadfence();
        atomicAdd(&bar2[mslab], 1);
        while (__hip_atomic_load(&bar2[mslab], __ATOMIC_ACQUIRE,
                                 __HIP_MEMORY_SCOPE_AGENT) < 8)
            __builtin_amdgcn_s_sleep(2);
    }
    __syncthreads();

    // ---- broadcast out: this block writes its 32 rows ----
    const int rstart = m0 + (dir * 4 + nblk) * 32;
    #pragma unroll
    for (int i = 0; i < 8; ++i) {
        const int row = rstart + i * 4 + (tid >> 7);
        const float val = hsum[row] * (1.0f / 512.0f);
        f32x4 vv = {val, val, val, val};
        ((f32x4*)(out + (size_t)row * 512))[tid & 127] = vv;
    }
}

extern "C" void kernel_launch(void* const* d_in, const int* in_sizes, int n_in,
                              void* d_out, int out_size, void* d_ws, size_t ws_size,
                              hipStream_t stream) {
    const float* emb  = (const float*)d_in[0];
    const float* wihf = (const float*)d_in[1];
    const float* whhf = (const float*)d_in[2];
    const float* bf   = (const float*)d_in[3];
    const float* wihb = (const float*)d_in[4];
    const float* whhb = (const float*)d_in[5];
    const float* bb   = (const float*)d_in[6];
    const int*   idx  = (const int*)d_in[7];
    float* out = (float*)d_out;

    // workspace layout (bytes)
    char* ws = (char*)d_ws;
    unsigned short* X     = (unsigned short*)(ws);               // 83,886,080
    unsigned short* Wcat  = (unsigned short*)(ws + 83886080);    //  2,097,152
    float*          bperm = (float*)(ws + 85983232);             //      8,192
    unsigned short* hping = (unsigned short*)(ws + 85991424);    // 16,777,216
    float*          hsum  = (float*)(ws + 102768640);            //     32,768
    int*            bar   = (int*)(ws + 102801408);              //        256
    int*            bar2  = (int*)(ws + 102801664);              //        128
    // total: 102,801,792 B

    hipMemsetAsync(hping, 0, 8388608, stream);        // h ping0, both dirs
    hipMemsetAsync(hsum, 0, 32768 + 256 + 128, stream); // hsum + bar + bar2

    convert_w<<<4096, 256, 0, stream>>>(wihf, whhf, bf, wihb, whhb, bb, Wcat, bperm);
    lstm_persist<<<256, 512, 0, stream>>>(emb, idx, X, Wcat, bperm, hping,
                                          hsum, bar, bar2, out);
}